// Round 6
// baseline (451.709 us; speedup 1.0000x reference)
//
#include <hip/hip_runtime.h>
#include <math.h>

typedef unsigned short u16;
typedef short s16x8 __attribute__((ext_vector_type(8)));
typedef float f32x4 __attribute__((ext_vector_type(4)));
typedef u16 u16x4 __attribute__((ext_vector_type(4)));
typedef int i32x4 __attribute__((ext_vector_type(4)));

#define D 1024
#define MM 2048   // B*S
#define HH 512
#define VV 32000

static __device__ __forceinline__ u16 f2bf(float f) {
    union { float f; unsigned int i; } c; c.f = f;
    unsigned int x = c.i;
    return (u16)((x + 0x7fffu + ((x >> 16) & 1u)) >> 16);  // RNE
}
static __device__ __forceinline__ float sigm(float x) { return 1.0f / (1.0f + expf(-x)); }

// async global->LDS, 16B per lane, LDS dest = wave-uniform base + lane*16
static __device__ __forceinline__ void load_lds16(const u16* g, u16* l) {
    __builtin_amdgcn_global_load_lds(
        (const __attribute__((address_space(1))) unsigned int*)g,
        (__attribute__((address_space(3))) unsigned int*)l, 16, 0, 0);
}

// ---------------- f32 -> bf16 convert ----------------
__global__ __launch_bounds__(256) void cvt_kernel(const float* __restrict__ in,
                                                  u16* __restrict__ out, const int n4)
{
    for (int i = blockIdx.x * 256 + threadIdx.x; i < n4; i += gridDim.x * 256) {
        f32x4 v = ((const f32x4*)in)[i];
        u16x4 o;
#pragma unroll
        for (int j = 0; j < 4; j++) o[j] = f2bf(v[j]);
        ((u16x4*)out)[i] = o;
    }
}

// ---------------- embed ----------------
__global__ __launch_bounds__(256) void embed_kernel(const int* __restrict__ ids,
    const float* __restrict__ emb, const float* __restrict__ pos, float* __restrict__ h)
{
    const int m = blockIdx.x;
    const int s = m & 1023;
    const long id = ids[m];
    const int d = threadIdx.x * 4;
    f32x4 ev = *(const f32x4*)&emb[id * D + d];
    f32x4 pv = *(const f32x4*)&pos[(long)s * D + d];
    f32x4 o;
#pragma unroll
    for (int i = 0; i < 4; i++) o[i] = ev[i] + pv[i];
    *(f32x4*)&h[(long)m * D + d] = o;
}

// ---------------- layernorm(f32) -> bf16 ----------------
__global__ __launch_bounds__(256) void ln_bf16_kernel(const float* __restrict__ h,
    u16* __restrict__ out, const float* __restrict__ g, const float* __restrict__ b)
{
    const int row = blockIdx.x;
    const int d = threadIdx.x * 4;
    f32x4 x = *(const f32x4*)&h[(long)row * D + d];
    float s = x[0] + x[1] + x[2] + x[3];
    float ss = x[0]*x[0] + x[1]*x[1] + x[2]*x[2] + x[3]*x[3];
#pragma unroll
    for (int off = 32; off; off >>= 1) { s += __shfl_xor(s, off); ss += __shfl_xor(ss, off); }
    __shared__ float red[8];
    const int wid = threadIdx.x >> 6;
    if ((threadIdx.x & 63) == 0) { red[wid] = s; red[4 + wid] = ss; }
    __syncthreads();
    s = red[0] + red[1] + red[2] + red[3];
    ss = red[4] + red[5] + red[6] + red[7];
    const float mu = s * (1.0f / D);
    const float rstd = rsqrtf(ss * (1.0f / D) - mu * mu + 1e-5f);
    f32x4 gv = *(const f32x4*)&g[d];
    f32x4 bv = *(const f32x4*)&b[d];
    u16x4 o;
#pragma unroll
    for (int i = 0; i < 4; i++) o[i] = f2bf((x[i] - mu) * rstd * gv[i] + bv[i]);
    *(u16x4*)&out[(long)row * D + d] = o;
}

// ---------------- h = LN(h + 0.3*C) ----------------
__global__ __launch_bounds__(256) void resln_kernel(float* __restrict__ h,
    const float* __restrict__ c, const float* __restrict__ g, const float* __restrict__ b)
{
    const int row = blockIdx.x;
    const int d = threadIdx.x * 4;
    f32x4 x = *(const f32x4*)&h[(long)row * D + d];
    f32x4 cv = *(const f32x4*)&c[(long)row * D + d];
#pragma unroll
    for (int i = 0; i < 4; i++) x[i] += 0.3f * cv[i];
    float s = x[0] + x[1] + x[2] + x[3];
    float ss = x[0]*x[0] + x[1]*x[1] + x[2]*x[2] + x[3]*x[3];
#pragma unroll
    for (int off = 32; off; off >>= 1) { s += __shfl_xor(s, off); ss += __shfl_xor(ss, off); }
    __shared__ float red[8];
    const int wid = threadIdx.x >> 6;
    if ((threadIdx.x & 63) == 0) { red[wid] = s; red[4 + wid] = ss; }
    __syncthreads();
    s = red[0] + red[1] + red[2] + red[3];
    ss = red[4] + red[5] + red[6] + red[7];
    const float mu = s * (1.0f / D);
    const float rstd = rsqrtf(ss * (1.0f / D) - mu * mu + 1e-5f);
    f32x4 gv = *(const f32x4*)&g[d];
    f32x4 bv = *(const f32x4*)&b[d];
    f32x4 o;
#pragma unroll
    for (int i = 0; i < 4; i++) o[i] = (x[i] - mu) * rstd * gv[i] + bv[i];
    *(f32x4*)&h[(long)row * D + d] = o;
}

// ---------------- exc scales ----------------
__global__ void exc_kernel(const float* __restrict__ pW, const float* __restrict__ pb,
                           float* __restrict__ sc)
{
    if (threadIdx.x == 0 && blockIdx.x == 0) {
        const float NS = 1.0f / (1.0f + expf(-0.70710678118654752f));
        float e[4], sum = 0.0f;
        for (int k = 0; k < 4; k++) {
            float a = pb[k];
            for (int j = 0; j < 4; j++) a += 0.5f * pW[k * 4 + j];
            e[k] = 0.6f * sigm(a) + 0.4f * NS;
            sum += e[k];
        }
        for (int k = 0; k < 4; k++) sc[k] = e[k] / sum;
    }
}

// ---------------- W2eff scale+convert ----------------
__global__ __launch_bounds__(256) void scale_w2_kernel(
    const float* __restrict__ W2l, const float* __restrict__ gatel,
    const float* __restrict__ tors, const float* __restrict__ sc,
    u16* __restrict__ W2eff)
{
    const int n = blockIdx.x >> 1;
    const int half = blockIdx.x & 1;
    const int kh = half * 1024 + threadIdx.x * 4;
    const int k = kh >> 9;
    const int hh = kh & 511;
    const float f = sigm(gatel[k * D + n] + tors[n]) * sc[k];
    f32x4 w = *(const f32x4*)&W2l[((long)k * D + n) * HH + hh];
    u16x4 o;
#pragma unroll
    for (int i = 0; i < 4; i++) o[i] = f2bf(w[i] * f);
    *(u16x4*)&W2eff[(long)n * 2048 + kh] = o;
}

// ---------------- layer GEMM (m97 structure, 128xBN tile) ----------------
template<int EPI, int BN>
__global__ __launch_bounds__(256) void gemm_lds_kernel(
    const u16* __restrict__ A, const u16* __restrict__ W,
    float* __restrict__ Cf, u16* __restrict__ Cb,
    const int K, const long ldc, const long strideWz, const long strideCz)
{
    W += (long)blockIdx.z * strideWz;
    if (EPI == 1) Cb += (long)blockIdx.z * strideCz;
    else          Cf += (long)blockIdx.z * strideCz;

    const int gx = gridDim.x;
    const int nwg = gx * gridDim.y;
    int lin = blockIdx.y * gx + blockIdx.x;
    lin = (lin & 7) * (nwg >> 3) + (lin >> 3);
    const int bm = (lin % gx) * 128;
    const int bn = (lin / gx) * BN;

    __shared__ __align__(16) u16 As[128 * 32];
    __shared__ __align__(16) u16 Bs[BN * 32];

    const int tid = threadIdx.x;
    const int lane = tid & 63;
    const int w = tid >> 6;
    const int wm = (w >> 1) * 64;
    const int wn = (w & 1) * (BN / 2);
    const int lr = lane & 15;
    const int lkb = (lane >> 4) * 16;

    const int srow = lane >> 2;
    const int scol = (lane & 3) * 8;

    constexpr int NA = 8;
    constexpr int NB = BN / 16;
    constexpr int NIT = (NA + NB) / 4;

    f32x4 acc[4][BN / 32];
#pragma unroll
    for (int i = 0; i < 4; i++)
#pragma unroll
        for (int j = 0; j < BN / 32; j++) acc[i][j] = f32x4{0.f, 0.f, 0.f, 0.f};

    for (int k0 = 0; k0 < K; k0 += 32) {
        __syncthreads();
#pragma unroll
        for (int it = 0; it < NIT; ++it) {
            const int c = w + it * 4;
            if (c < NA) {
                load_lds16(&A[(long)(bm + c * 16 + srow) * K + k0 + scol], &As[c * 512]);
            } else {
                const int c2 = c - NA;
                load_lds16(&W[(long)(bn + c2 * 16 + srow) * K + k0 + scol], &Bs[c2 * 512]);
            }
        }
        __syncthreads();
        s16x8 a[4], b[BN / 32];
#pragma unroll
        for (int i = 0; i < 4; i++)
            a[i] = *(const s16x8*)((const char*)As + (wm + i * 16 + lr) * 64 + lkb);
#pragma unroll
        for (int j = 0; j < BN / 32; j++)
            b[j] = *(const s16x8*)((const char*)Bs + (wn + j * 16 + lr) * 64 + lkb);
#pragma unroll
        for (int i = 0; i < 4; i++)
#pragma unroll
            for (int j = 0; j < BN / 32; j++)
                acc[i][j] = __builtin_amdgcn_mfma_f32_16x16x32_bf16(a[i], b[j], acc[i][j], 0, 0, 0);
    }

    const int r0 = (lane >> 4) * 4;
#pragma unroll
    for (int i = 0; i < 4; i++) {
#pragma unroll
        for (int j = 0; j < BN / 32; j++) {
            const int n = bn + wn + j * 16 + lr;
#pragma unroll
            for (int r = 0; r < 4; r++) {
                const int m = bm + wm + i * 16 + r0 + r;
                const float v = acc[i][j][r];
                if (EPI == 0) {
                    Cf[(long)m * ldc + n] = v;
                } else if (EPI == 1) {
                    const float gel = 0.5f * v * (1.0f + erff(v * 0.70710678118654752f));
                    Cb[(long)m * ldc + n] = f2bf(gel);
                } else {
                    Cf[(long)m * ldc + n] += v;
                }
            }
        }
    }
}

// ================= lm_head GEMM: 256x256 tile, BK=32, 8-phase counted-vmcnt =================
// C[2048,32000] = A[2048,1024] @ W[32000,1024]^T. 512 thr (8 waves), 64KB LDS
// (2 bufs x {A,B} x 2 halves of 128x32 bf16). Per K-tile: 4 phases, each = one
// 128x128 C-quadrant (Q00,Q10,Q01,Q11). Each phase stages exactly the half-tile
// slot that died last phase; vmcnt(2) only at phases 4/8 (T4). T2 16B-slot XOR
// swizzle (both-sides involution). T5 setprio around MFMA cluster.

// stage one 128x32 half-tile: thread -> row wid*16+(lane>>2), 16B slot (lane&3)^(row&3)
static __device__ __forceinline__ void stageHalf(u16* slot, const u16* g, int wid, int lane) {
    const int r = wid * 16 + (lane >> 2);
    const int c16 = (lane & 3) ^ ((lane >> 2) & 3);
    load_lds16(g + (long)r * 1024 + c16 * 8, slot + wid * 512);
}
// swizzled ds_read of one 16x32 MFMA fragment
static __device__ __forceinline__ s16x8 ldsFrag(const u16* slot, int fr, int lane) {
    const int row = fr + (lane & 15);
    const int c16 = (lane >> 4) ^ (row & 3);
    return *(const s16x8*)(slot + row * 32 + c16 * 8);
}

#define SLOT(ab, buf, half) (lds[((ab) << 2) | ((buf) << 1) | (half)])
#define VMCNT2() asm volatile("s_waitcnt vmcnt(2)" ::: "memory")
#define SBAR()   do { __builtin_amdgcn_s_barrier(); __builtin_amdgcn_sched_barrier(0); } while (0)

#define PHASE(qm, qn, rb, STAGE_STMT, DO_VM)                                        \
    do {                                                                            \
        s16x8 af[2], bf[4];                                                         \
        _Pragma("unroll") for (int ii = 0; ii < 2; ++ii)                            \
            af[ii] = ldsFrag(SLOT(0, rb, qm), fmBase + ii * 16, lane);              \
        _Pragma("unroll") for (int jj = 0; jj < 4; ++jj)                            \
            bf[jj] = ldsFrag(SLOT(1, rb, qn), fnBase + jj * 16, lane);              \
        STAGE_STMT;                                                                 \
        SBAR();                                                                     \
        __builtin_amdgcn_s_setprio(1);                                              \
        _Pragma("unroll") for (int ii = 0; ii < 2; ++ii)                            \
            _Pragma("unroll") for (int jj = 0; jj < 4; ++jj)                        \
                acc[qm][qn][ii][jj] = __builtin_amdgcn_mfma_f32_16x16x32_bf16(      \
                    af[ii], bf[jj], acc[qm][qn][ii][jj], 0, 0, 0);                  \
        __builtin_amdgcn_s_setprio(0);                                              \
        if (DO_VM) VMCNT2();                                                        \
        SBAR();                                                                     \
    } while (0)

__global__ __launch_bounds__(512, 2) void gemm256_kernel(
    const u16* __restrict__ Ag, const u16* __restrict__ Wg, float* __restrict__ C)
{
    // XCD-chunked bijective swizzle (nwg = 8*125 = 1000, %8==0)
    const int nwg = gridDim.x * gridDim.y;   // gridDim.x = 8 (M)
    int lin = blockIdx.y * gridDim.x + blockIdx.x;
    lin = (lin & 7) * (nwg >> 3) + (lin >> 3);
    const int bm = (lin & 7) * 256;          // 8 M-tiles of one W-panel stay on one XCD
    const int bn = (lin >> 3) * 256;

    __shared__ __align__(16) u16 lds[8][128 * 32];  // [ab*4|buf*2|half] = 8 x 8KB = 64KB

    const int tid = threadIdx.x;
    const int lane = tid & 63;
    const int w = tid >> 6;                 // 0..7
    const int fmBase = (w & 3) * 32;        // wave's 2 A-frag rows within the 128-half
    const int fnBase = (w >> 2) * 64;       // wave's 4 B-frag rows within the 128-half

    f32x4 acc[2][2][2][4];
#pragma unroll
    for (int a0 = 0; a0 < 2; ++a0)
#pragma unroll
        for (int a1 = 0; a1 < 2; ++a1)
#pragma unroll
            for (int a2 = 0; a2 < 2; ++a2)
#pragma unroll
                for (int a3 = 0; a3 < 4; ++a3) acc[a0][a1][a2][a3] = f32x4{0.f, 0.f, 0.f, 0.f};

    // prologue: tile0 complete + tile1 {B0, A0}; vmcnt(2) -> tile0 landed
    stageHalf(SLOT(0, 0, 0), Ag + (long)(bm      ) * 1024,      w, lane);  // A0(0)
    stageHalf(SLOT(1, 0, 0), Wg + (long)(bn      ) * 1024,      w, lane);  // B0(0)
    stageHalf(SLOT(0, 0, 1), Ag + (long)(bm + 128) * 1024,      w, lane);  // A1(0)
    stageHalf(SLOT(1, 0, 1), Wg + (long)(bn + 128) * 1024,      w, lane);  // B1(0)
    stageHalf(SLOT(1, 1, 0), Wg + (long)(bn      ) * 1024 + 32, w, lane);  // B0(1)
    stageHalf(SLOT(0, 1, 0), Ag + (long)(bm      ) * 1024 + 32, w, lane);  // A0(1)
    VMCNT2();
    SBAR();

    for (int i = 0; i < 16; ++i) {
        const int t = 2 * i;
        const long k1 = (long)(t + 1) * 32;          // never wraps (<=31)
        const long k2 = (long)((t + 2) & 31) * 32;   // wraps to dead-slot dummy at end
        const long k3 = (long)((t + 3) & 31) * 32;

        // tile t (buf0): Q00, Q10, Q01, Q11
        PHASE(0, 0, 0, stageHalf(SLOT(0, 1, 1), Ag + (long)(bm + 128) * 1024 + k1, w, lane), 0); // A1(t+1)
        PHASE(1, 0, 0, stageHalf(SLOT(1, 1, 1), Wg + (long)(bn + 128) * 1024 + k1, w, lane), 0); // B1(t+1)
        PHASE(0, 1, 0, stageHalf(SLOT(1, 0, 0), Wg + (long)(bn      ) * 1024 + k2, w, lane), 0); // B0(t+2)
        PHASE(1, 1, 0, stageHalf(SLOT(0, 0, 0), Ag + (long)(bm      ) * 1024 + k2, w, lane), 1); // A0(t+2), vmcnt
        // tile t+1 (buf1): Q00, Q10, Q01, Q11
        PHASE(0, 0, 1, stageHalf(SLOT(0, 0, 1), Ag + (long)(bm + 128) * 1024 + k2, w, lane), 0); // A1(t+2)
        PHASE(1, 0, 1, stageHalf(SLOT(1, 0, 1), Wg + (long)(bn + 128) * 1024 + k2, w, lane), 0); // B1(t+2)
        PHASE(0, 1, 1, stageHalf(SLOT(1, 1, 0), Wg + (long)(bn      ) * 1024 + k3, w, lane), 0); // B0(t+3)
        PHASE(1, 1, 1, stageHalf(SLOT(0, 1, 0), Ag + (long)(bm      ) * 1024 + k3, w, lane), 1); // A0(t+3), vmcnt
    }

    // epilogue: C/D layout col = lane&15, row = (lane>>4)*4 + reg
    const int r0 = (lane >> 4) * 4;
    const int cl = lane & 15;
#pragma unroll
    for (int qm = 0; qm < 2; ++qm)
#pragma unroll
        for (int qn = 0; qn < 2; ++qn)
#pragma unroll
            for (int ii = 0; ii < 2; ++ii)
#pragma unroll
                for (int jj = 0; jj < 4; ++jj) {
                    const int m = bm + qm * 128 + fmBase + ii * 16 + r0;
                    const int n = bn + qn * 128 + fnBase + jj * 16 + cl;
#pragma unroll
                    for (int rr = 0; rr < 4; ++rr)
                        C[(long)(m + rr) * VV + n] = acc[qm][qn][ii][jj][rr];
                }
}

extern "C" void kernel_launch(void* const* d_in, const int* in_sizes, int n_in,
                              void* d_out, int out_size, void* d_ws, size_t ws_size,
                              hipStream_t stream)
{
    (void)in_sizes; (void)n_in; (void)out_size; (void)ws_size;
    const int*   ids   = (const int*)d_in[0];
    const float* emb   = (const float*)d_in[1];
    const float* pos   = (const float*)d_in[2];
    const float* tors  = (const float*)d_in[3];
    const float* ln1g  = (const float*)d_in[4];
    const float* ln1b  = (const float*)d_in[5];
    const float* baseW = (const float*)d_in[6];
    const float* W1    = (const float*)d_in[7];
    const float* W2    = (const float*)d_in[8];
    const float* gate  = (const float*)d_in[9];
    const float* propW = (const float*)d_in[10];
    const float* propb = (const float*)d_in[11];
    const float* ln2g  = (const float*)d_in[12];
    const float* ln2b  = (const float*)d_in[13];
    const float* outg  = (const float*)d_in[14];
    const float* outb  = (const float*)d_in[15];
    const float* lmW   = (const float*)d_in[16];

    char* ws = (char*)d_ws;
    float* h     = (float*)(ws);                    // 0..8 MB
    u16*   hn    = (u16*)  (ws + (8l  << 20));      // 8..12 MB
    u16*   bWbf  = (u16*)  (ws + (12l << 20));      // 12..14 MB
    u16*   W1bf  = (u16*)  (ws + (14l << 20));      // 14..18 MB
    float* C     = (float*)(ws + (18l << 20));      // 18..26 MB
    u16*   t     = (u16*)  (ws + (26l << 20));      // 26..34 MB
    u16*   W2eff = (u16*)  (ws + (34l << 20));      // 34..38 MB
    float* sc    = (float*)(ws + (38l << 20));      // 16 B
    u16*   lmWbf = (u16*)  (ws + (12l << 20));      // overlay: 12..74.5 MB

    embed_kernel<<<MM, 256, 0, stream>>>(ids, emb, pos, h);

    for (int l = 0; l < 2; l++) {
        exc_kernel<<<1, 64, 0, stream>>>(propW + l * 16, propb + l * 4, sc);
        ln_bf16_kernel<<<MM, 256, 0, stream>>>(h, hn, ln1g + (long)l * D, ln1b + (long)l * D);
        cvt_kernel<<<1024, 256, 0, stream>>>(baseW + (long)l * D * D, bWbf, D * D / 4);
        cvt_kernel<<<2048, 256, 0, stream>>>(W1 + (long)l * 4 * HH * D, W1bf, 4 * HH * D / 4);
        gemm_lds_kernel<0, 64><<<dim3(16, 16, 1), 256, 0, stream>>>(
            hn, bWbf, C, nullptr, D, D, 0, 0);
        gemm_lds_kernel<1, 64><<<dim3(16, 8, 4), 256, 0, stream>>>(
            hn, W1bf, nullptr, t, D, 2048, (long)HH * D, 512);
        scale_w2_kernel<<<2048, 256, 0, stream>>>(
            W2 + (long)l * 4 * D * HH, gate + (long)l * 4 * D, tors, sc, W2eff);
        gemm_lds_kernel<2, 64><<<dim3(16, 16, 1), 256, 0, stream>>>(
            t, W2eff, C, nullptr, 2048, D, 0, 0);
        resln_kernel<<<MM, 256, 0, stream>>>(h, C, ln2g + (long)l * D, ln2b + (long)l * D);
    }

    ln_bf16_kernel<<<MM, 256, 0, stream>>>(h, hn, outg, outb);
    cvt_kernel<<<2048, 256, 0, stream>>>(lmW, lmWbf, VV * D / 4);
    // lm_head: 256^2 8-phase counted-vmcnt GEMM
    gemm256_kernel<<<dim3(8, 125), 512, 0, stream>>>(hn, lmWbf, (float*)d_out);
}

// Round 7
// 442.782 us; speedup vs baseline: 1.0202x; 1.0202x over previous
//
#include <hip/hip_runtime.h>
#include <math.h>

typedef unsigned short u16;
typedef short s16x8 __attribute__((ext_vector_type(8)));
typedef float f32x4 __attribute__((ext_vector_type(4)));
typedef u16 u16x4 __attribute__((ext_vector_type(4)));
typedef int i32x4 __attribute__((ext_vector_type(4)));

#define D 1024
#define MM 2048   // B*S
#define HH 512
#define VV 32000

static __device__ __forceinline__ u16 f2bf(float f) {
    union { float f; unsigned int i; } c; c.f = f;
    unsigned int x = c.i;
    return (u16)((x + 0x7fffu + ((x >> 16) & 1u)) >> 16);  // RNE
}
static __device__ __forceinline__ float sigm(float x) { return 1.0f / (1.0f + expf(-x)); }

// async global->LDS, 16B per lane, LDS dest = wave-uniform base + lane*16
static __device__ __forceinline__ void load_lds16(const u16* g, u16* l) {
    __builtin_amdgcn_global_load_lds(
        (const __attribute__((address_space(1))) unsigned int*)g,
        (__attribute__((address_space(3))) unsigned int*)l, 16, 0, 0);
}

// ---------------- f32 -> bf16 convert ----------------
__global__ __launch_bounds__(256) void cvt_kernel(const float* __restrict__ in,
                                                  u16* __restrict__ out, const int n4)
{
    for (int i = blockIdx.x * 256 + threadIdx.x; i < n4; i += gridDim.x * 256) {
        f32x4 v = ((const f32x4*)in)[i];
        u16x4 o;
#pragma unroll
        for (int j = 0; j < 4; j++) o[j] = f2bf(v[j]);
        ((u16x4*)out)[i] = o;
    }
}

// ---------------- embed ----------------
__global__ __launch_bounds__(256) void embed_kernel(const int* __restrict__ ids,
    const float* __restrict__ emb, const float* __restrict__ pos, float* __restrict__ h)
{
    const int m = blockIdx.x;
    const int s = m & 1023;
    const long id = ids[m];
    const int d = threadIdx.x * 4;
    f32x4 ev = *(const f32x4*)&emb[id * D + d];
    f32x4 pv = *(const f32x4*)&pos[(long)s * D + d];
    f32x4 o;
#pragma unroll
    for (int i = 0; i < 4; i++) o[i] = ev[i] + pv[i];
    *(f32x4*)&h[(long)m * D + d] = o;
}

// ---------------- layernorm(f32) -> bf16 ----------------
__global__ __launch_bounds__(256) void ln_bf16_kernel(const float* __restrict__ h,
    u16* __restrict__ out, const float* __restrict__ g, const float* __restrict__ b)
{
    const int row = blockIdx.x;
    const int d = threadIdx.x * 4;
    f32x4 x = *(const f32x4*)&h[(long)row * D + d];
    float s = x[0] + x[1] + x[2] + x[3];
    float ss = x[0]*x[0] + x[1]*x[1] + x[2]*x[2] + x[3]*x[3];
#pragma unroll
    for (int off = 32; off; off >>= 1) { s += __shfl_xor(s, off); ss += __shfl_xor(ss, off); }
    __shared__ float red[8];
    const int wid = threadIdx.x >> 6;
    if ((threadIdx.x & 63) == 0) { red[wid] = s; red[4 + wid] = ss; }
    __syncthreads();
    s = red[0] + red[1] + red[2] + red[3];
    ss = red[4] + red[5] + red[6] + red[7];
    const float mu = s * (1.0f / D);
    const float rstd = rsqrtf(ss * (1.0f / D) - mu * mu + 1e-5f);
    f32x4 gv = *(const f32x4*)&g[d];
    f32x4 bv = *(const f32x4*)&b[d];
    u16x4 o;
#pragma unroll
    for (int i = 0; i < 4; i++) o[i] = f2bf((x[i] - mu) * rstd * gv[i] + bv[i]);
    *(u16x4*)&out[(long)row * D + d] = o;
}

// ---------------- h = LN(h + 0.3*C) ----------------
__global__ __launch_bounds__(256) void resln_kernel(float* __restrict__ h,
    const float* __restrict__ c, const float* __restrict__ g, const float* __restrict__ b)
{
    const int row = blockIdx.x;
    const int d = threadIdx.x * 4;
    f32x4 x = *(const f32x4*)&h[(long)row * D + d];
    f32x4 cv = *(const f32x4*)&c[(long)row * D + d];
#pragma unroll
    for (int i = 0; i < 4; i++) x[i] += 0.3f * cv[i];
    float s = x[0] + x[1] + x[2] + x[3];
    float ss = x[0]*x[0] + x[1]*x[1] + x[2]*x[2] + x[3]*x[3];
#pragma unroll
    for (int off = 32; off; off >>= 1) { s += __shfl_xor(s, off); ss += __shfl_xor(ss, off); }
    __shared__ float red[8];
    const int wid = threadIdx.x >> 6;
    if ((threadIdx.x & 63) == 0) { red[wid] = s; red[4 + wid] = ss; }
    __syncthreads();
    s = red[0] + red[1] + red[2] + red[3];
    ss = red[4] + red[5] + red[6] + red[7];
    const float mu = s * (1.0f / D);
    const float rstd = rsqrtf(ss * (1.0f / D) - mu * mu + 1e-5f);
    f32x4 gv = *(const f32x4*)&g[d];
    f32x4 bv = *(const f32x4*)&b[d];
    f32x4 o;
#pragma unroll
    for (int i = 0; i < 4; i++) o[i] = (x[i] - mu) * rstd * gv[i] + bv[i];
    *(f32x4*)&h[(long)row * D + d] = o;
}

// ---------------- exc scales ----------------
__global__ void exc_kernel(const float* __restrict__ pW, const float* __restrict__ pb,
                           float* __restrict__ sc)
{
    if (threadIdx.x == 0 && blockIdx.x == 0) {
        const float NS = 1.0f / (1.0f + expf(-0.70710678118654752f));
        float e[4], sum = 0.0f;
        for (int k = 0; k < 4; k++) {
            float a = pb[k];
            for (int j = 0; j < 4; j++) a += 0.5f * pW[k * 4 + j];
            e[k] = 0.6f * sigm(a) + 0.4f * NS;
            sum += e[k];
        }
        for (int k = 0; k < 4; k++) sc[k] = e[k] / sum;
    }
}

// ---------------- W2eff scale+convert ----------------
__global__ __launch_bounds__(256) void scale_w2_kernel(
    const float* __restrict__ W2l, const float* __restrict__ gatel,
    const float* __restrict__ tors, const float* __restrict__ sc,
    u16* __restrict__ W2eff)
{
    const int n = blockIdx.x >> 1;
    const int half = blockIdx.x & 1;
    const int kh = half * 1024 + threadIdx.x * 4;
    const int k = kh >> 9;
    const int hh = kh & 511;
    const float f = sigm(gatel[k * D + n] + tors[n]) * sc[k];
    f32x4 w = *(const f32x4*)&W2l[((long)k * D + n) * HH + hh];
    u16x4 o;
#pragma unroll
    for (int i = 0; i < 4; i++) o[i] = f2bf(w[i] * f);
    *(u16x4*)&W2eff[(long)n * 2048 + kh] = o;
}

// ---------------- layer GEMM (m97 structure, 128xBN tile) ----------------
template<int EPI, int BN>
__global__ __launch_bounds__(256) void gemm_lds_kernel(
    const u16* __restrict__ A, const u16* __restrict__ W,
    float* __restrict__ Cf, u16* __restrict__ Cb,
    const int K, const long ldc, const long strideWz, const long strideCz)
{
    W += (long)blockIdx.z * strideWz;
    if (EPI == 1) Cb += (long)blockIdx.z * strideCz;
    else          Cf += (long)blockIdx.z * strideCz;

    const int gx = gridDim.x;
    const int nwg = gx * gridDim.y;
    int lin = blockIdx.y * gx + blockIdx.x;
    lin = (lin & 7) * (nwg >> 3) + (lin >> 3);
    const int bm = (lin % gx) * 128;
    const int bn = (lin / gx) * BN;

    __shared__ __align__(16) u16 As[128 * 32];
    __shared__ __align__(16) u16 Bs[BN * 32];

    const int tid = threadIdx.x;
    const int lane = tid & 63;
    const int w = tid >> 6;
    const int wm = (w >> 1) * 64;
    const int wn = (w & 1) * (BN / 2);
    const int lr = lane & 15;
    const int lkb = (lane >> 4) * 16;

    const int srow = lane >> 2;
    const int scol = (lane & 3) * 8;

    constexpr int NA = 8;
    constexpr int NB = BN / 16;
    constexpr int NIT = (NA + NB) / 4;

    f32x4 acc[4][BN / 32];
#pragma unroll
    for (int i = 0; i < 4; i++)
#pragma unroll
        for (int j = 0; j < BN / 32; j++) acc[i][j] = f32x4{0.f, 0.f, 0.f, 0.f};

    for (int k0 = 0; k0 < K; k0 += 32) {
        __syncthreads();
#pragma unroll
        for (int it = 0; it < NIT; ++it) {
            const int c = w + it * 4;
            if (c < NA) {
                load_lds16(&A[(long)(bm + c * 16 + srow) * K + k0 + scol], &As[c * 512]);
            } else {
                const int c2 = c - NA;
                load_lds16(&W[(long)(bn + c2 * 16 + srow) * K + k0 + scol], &Bs[c2 * 512]);
            }
        }
        __syncthreads();
        s16x8 a[4], b[BN / 32];
#pragma unroll
        for (int i = 0; i < 4; i++)
            a[i] = *(const s16x8*)((const char*)As + (wm + i * 16 + lr) * 64 + lkb);
#pragma unroll
        for (int j = 0; j < BN / 32; j++)
            b[j] = *(const s16x8*)((const char*)Bs + (wn + j * 16 + lr) * 64 + lkb);
#pragma unroll
        for (int i = 0; i < 4; i++)
#pragma unroll
            for (int j = 0; j < BN / 32; j++)
                acc[i][j] = __builtin_amdgcn_mfma_f32_16x16x32_bf16(a[i], b[j], acc[i][j], 0, 0, 0);
    }

    const int r0 = (lane >> 4) * 4;
#pragma unroll
    for (int i = 0; i < 4; i++) {
#pragma unroll
        for (int j = 0; j < BN / 32; j++) {
            const int n = bn + wn + j * 16 + lr;
#pragma unroll
            for (int r = 0; r < 4; r++) {
                const int m = bm + wm + i * 16 + r0 + r;
                const float v = acc[i][j][r];
                if (EPI == 0) {
                    Cf[(long)m * ldc + n] = v;
                } else if (EPI == 1) {
                    const float gel = 0.5f * v * (1.0f + erff(v * 0.70710678118654752f));
                    Cb[(long)m * ldc + n] = f2bf(gel);
                } else {
                    Cf[(long)m * ldc + n] += v;
                }
            }
        }
    }
}

// ================= lm_head GEMM: 256x256, BK=64, 4 balanced phases/K-tile =================
// C[2048,32000] = A[2048,1024] @ W[32000,1024]^T, f32 out. 512 thr = 8 waves (2M x 4N),
// per-wave output 128x64. LDS 128KB: per buf, A = 2 halves x 8 frags x 2 kk-slices of
// (64 lanes x 16B) FRAGMENT-LINEAR chunks -> every ds_read/write is base+lane*16:
// zero bank conflicts by construction (staging pre-swizzles the GLOBAL address).
// Phases per K-tile: (kk0,nh0) (kk0,nh1) (kk1,nh0) (kk1,nh1); A-frags held in regs
// across each nh-pair -> 24 ds_read_b128 per wave per K-tile (minimum).
// Stage units = 16KB kk-slices; each phase stages the unit that died last phase;
// vmcnt(6) once per K-tile (T4); setprio around MFMA (T5).

#define AU16  16384   // u16 per A (or B) buffer = 32KB
#define HALFU 8192    // u16 per 128-row half = 16KB
#define BB0   32768   // u16 offset of B region

#define BAR() do { __builtin_amdgcn_s_barrier(); __builtin_amdgcn_sched_barrier(0); } while (0)

__global__ __launch_bounds__(512, 2) void gemm256_kernel(
    const u16* __restrict__ Ag, const u16* __restrict__ Wg, float* __restrict__ C)
{
    __shared__ __align__(16) u16 lds[65536];  // 128KB

    // XCD-chunked bijective swizzle (nwg = 8*125 = 1000, %8 == 0)
    const int nwg = gridDim.x * gridDim.y;
    int lin = blockIdx.y * gridDim.x + blockIdx.x;
    lin = (lin & 7) * (nwg >> 3) + (lin >> 3);
    const int bm = (lin & 7) * 256;
    const int bn = (lin >> 3) * 256;

    const int tid = threadIdx.x;
    const int lane = tid & 63;
    const int w = tid >> 6;     // 0..7
    const int wm = w >> 2;      // 0..1  (M half)
    const int wn = w & 3;       // 0..3  (N quarter)

    // staging: wave w owns fragment-row fr=w of both halves; lane l supplies
    // global element (row = half*128 + w*16 + (l&15), k = kt*64 + kk*32 + (l>>4)*8)
    const u16* aSrc = Ag + (long)(bm + w * 16 + (lane & 15)) * 1024 + ((lane >> 4) * 8);
    const u16* bSrc = Wg + (long)(bn + w * 16 + (lane & 15)) * 1024 + ((lane >> 4) * 8);
    u16* aDst = lds + w * 1024;         // + b*AU16 + half*HALFU + kk*512 (wave-uniform)
    u16* bDst = lds + BB0 + w * 1024;

    auto stageA = [&](int kt, int b, int kk) {
        const long co = (long)kt * 64 + kk * 32;
        load_lds16(aSrc + co,               aDst + b * AU16 + kk * 512);
        load_lds16(aSrc + co + 128 * 1024L, aDst + b * AU16 + HALFU + kk * 512);
    };
    auto stageB = [&](int kt, int b, int kk) {
        const long co = (long)kt * 64 + kk * 32;
        load_lds16(bSrc + co,               bDst + b * AU16 + kk * 512);
        load_lds16(bSrc + co + 128 * 1024L, bDst + b * AU16 + HALFU + kk * 512);
    };

    // fragment-linear reads: chunk base + lane*8 (u16) = lane*16B -> conflict-free
    const u16* aRd = lds + wm * HALFU + lane * 8;                         // + b*AU16 + fr*1024 + kk*512
    const u16* bRd = lds + BB0 + (wn >> 1) * HALFU + (wn & 1) * 4096 + lane * 8;  // + b*AU16 + (nh*2+j)*1024 + kk*512

    f32x4 acc[8][4];
#pragma unroll
    for (int i = 0; i < 8; ++i)
#pragma unroll
        for (int j = 0; j < 4; ++j) acc[i][j] = f32x4{0.f, 0.f, 0.f, 0.f};

    // prologue: tile0 all 4 units + tile1 {A_k0, B_k0, A_k1}; vmcnt(6) -> tile0 landed
    stageA(0, 0, 0); stageB(0, 0, 0); stageA(0, 0, 1); stageB(0, 0, 1);
    stageA(1, 1, 0); stageB(1, 1, 0); stageA(1, 1, 1);
    asm volatile("s_waitcnt vmcnt(6)" ::: "memory");
    BAR();

    auto ktile = [&](int t, int b) {
        const int t1 = (t + 1) & 15, t2 = (t + 2) & 15;   // wrap -> dummy stages into dead units
        s16x8 af[8], bf[2];
        // P1: kk=0, nh=0   (reads U_A_k0 + U_B_k0/nh0; stages B_k1(t+1) into buf^1)
#pragma unroll
        for (int i = 0; i < 8; ++i) af[i] = *(const s16x8*)(aRd + b * AU16 + i * 1024);
#pragma unroll
        for (int j = 0; j < 2; ++j) bf[j] = *(const s16x8*)(bRd + b * AU16 + j * 1024);
        stageB(t1, b ^ 1, 1);
        BAR();
        __builtin_amdgcn_s_setprio(1);
#pragma unroll
        for (int i = 0; i < 8; ++i) {
            acc[i][0] = __builtin_amdgcn_mfma_f32_16x16x32_bf16(af[i], bf[0], acc[i][0], 0, 0, 0);
            acc[i][1] = __builtin_amdgcn_mfma_f32_16x16x32_bf16(af[i], bf[1], acc[i][1], 0, 0, 0);
        }
        __builtin_amdgcn_s_setprio(0);
        BAR();
        // P2: kk=0, nh=1   (af reused; U_A_k0 now dead -> stage A_k0(t+2))
#pragma unroll
        for (int j = 0; j < 2; ++j) bf[j] = *(const s16x8*)(bRd + b * AU16 + 2048 + j * 1024);
        stageA(t2, b, 0);
        BAR();
        __builtin_amdgcn_s_setprio(1);
#pragma unroll
        for (int i = 0; i < 8; ++i) {
            acc[i][2] = __builtin_amdgcn_mfma_f32_16x16x32_bf16(af[i], bf[0], acc[i][2], 0, 0, 0);
            acc[i][3] = __builtin_amdgcn_mfma_f32_16x16x32_bf16(af[i], bf[1], acc[i][3], 0, 0, 0);
        }
        __builtin_amdgcn_s_setprio(0);
        BAR();
        // P3: kk=1, nh=0   (U_B_k0 dead -> stage B_k0(t+2))
#pragma unroll
        for (int i = 0; i < 8; ++i) af[i] = *(const s16x8*)(aRd + b * AU16 + i * 1024 + 512);
#pragma unroll
        for (int j = 0; j < 2; ++j) bf[j] = *(const s16x8*)(bRd + b * AU16 + j * 1024 + 512);
        stageB(t2, b, 0);
        BAR();
        __builtin_amdgcn_s_setprio(1);
#pragma unroll
        for (int i = 0; i < 8; ++i) {
            acc[i][0] = __builtin_amdgcn_mfma_f32_16x16x32_bf16(af[i], bf[0], acc[i][0], 0, 0, 0);
            acc[i][1] = __builtin_amdgcn_mfma_f32_16x16x32_bf16(af[i], bf[1], acc[i][1], 0, 0, 0);
        }
        __builtin_amdgcn_s_setprio(0);
        BAR();
        // P4: kk=1, nh=1   (U_A_k1 dead -> stage A_k1(t+2); counted vmcnt once per K-tile)
#pragma unroll
        for (int j = 0; j < 2; ++j) bf[j] = *(const s16x8*)(bRd + b * AU16 + 2048 + j * 1024 + 512);
        stageA(t2, b, 1);
        BAR();
        __builtin_amdgcn_s_setprio(1);
#pragma unroll
        for (int i = 0; i < 8; ++i) {
            acc[i][2] = __builtin_amdgcn_mfma_f32_16x16x32_bf16(af[i], bf[0], acc[i][2], 0, 0, 0);
            acc[i][3] = __builtin_amdgcn_mfma_f32_16x16x32_bf16(af[i], bf[1], acc[i][3], 0, 0, 0);
        }
        __builtin_amdgcn_s_setprio(0);
        asm volatile("s_waitcnt vmcnt(6)" ::: "memory");
        BAR();
    };

    for (int tt = 0; tt < 8; ++tt) {
        ktile(2 * tt,     0);
        ktile(2 * tt + 1, 1);
    }

    // drain in-flight dummy stages before the block can retire/reuse LDS
    asm volatile("s_waitcnt vmcnt(0)" ::: "memory");

    // epilogue: C/D layout col = lane&15, row = (lane>>4)*4 + reg
    const int r0 = (lane >> 4) * 4;
    const int cl = lane & 15;
#pragma unroll
    for (int i = 0; i < 8; ++i)
#pragma unroll
        for (int j = 0; j < 4; ++j) {
            const long m = bm + wm * 128 + i * 16 + r0;
            const int n = bn + wn * 64 + j * 16 + cl;
#pragma unroll
            for (int rr = 0; rr < 4; ++rr)
                C[(m + rr) * (long)VV + n] = acc[i][j][rr];
        }
}

extern "C" void kernel_launch(void* const* d_in, const int* in_sizes, int n_in,
                              void* d_out, int out_size, void* d_ws, size_t ws_size,
                              hipStream_t stream)
{
    (void)in_sizes; (void)n_in; (void)out_size; (void)ws_size;
    const int*   ids   = (const int*)d_in[0];
    const float* emb   = (const float*)d_in[1];
    const float* pos   = (const float*)d_in[2];
    const float* tors  = (const float*)d_in[3];
    const float* ln1g  = (const float*)d_in[4];
    const float* ln1b  = (const float*)d_in[5];
    const float* baseW = (const float*)d_in[6];
    const float* W1    = (const float*)d_in[7];
    const float* W2    = (const float*)d_in[8];
    const float* gate  = (const float*)d_in[9];
    const float* propW = (const float*)d_in[10];
    const float* propb = (const float*)d_in[11];
    const float* ln2g  = (const float*)d_in[12];
    const float* ln2b  = (const float*)d_in[13];
    const float* outg  = (const float*)d_in[14];
    const float* outb  = (const float*)d_in[15];
    const float* lmW   = (const float*)d_in[16];

    char* ws = (char*)d_ws;
    float* h     = (float*)(ws);                    // 0..8 MB
    u16*   hn    = (u16*)  (ws + (8l  << 20));      // 8..12 MB
    u16*   bWbf  = (u16*)  (ws + (12l << 20));      // 12..14 MB
    u16*   W1bf  = (u16*)  (ws + (14l << 20));      // 14..18 MB
    float* C     = (float*)(ws + (18l << 20));      // 18..26 MB
    u16*   t     = (u16*)  (ws + (26l << 20));      // 26..34 MB
    u16*   W2eff = (u16*)  (ws + (34l << 20));      // 34..38 MB
    float* sc    = (float*)(ws + (38l << 20));      // 16 B
    u16*   lmWbf = (u16*)  (ws + (12l << 20));      // overlay: 12..74.5 MB

    embed_kernel<<<MM, 256, 0, stream>>>(ids, emb, pos, h);

    for (int l = 0; l < 2; l++) {
        exc_kernel<<<1, 64, 0, stream>>>(propW + l * 16, propb + l * 4, sc);
        ln_bf16_kernel<<<MM, 256, 0, stream>>>(h, hn, ln1g + (long)l * D, ln1b + (long)l * D);
        cvt_kernel<<<1024, 256, 0, stream>>>(baseW + (long)l * D * D, bWbf, D * D / 4);
        cvt_kernel<<<2048, 256, 0, stream>>>(W1 + (long)l * 4 * HH * D, W1bf, 4 * HH * D / 4);
        gemm_lds_kernel<0, 64><<<dim3(16, 16, 1), 256, 0, stream>>>(
            hn, bWbf, C, nullptr, D, D, 0, 0);
        gemm_lds_kernel<1, 64><<<dim3(16, 8, 4), 256, 0, stream>>>(
            hn, W1bf, nullptr, t, D, 2048, (long)HH * D, 512);
        scale_w2_kernel<<<2048, 256, 0, stream>>>(
            W2 + (long)l * 4 * D * HH, gate + (long)l * 4 * D, tors, sc, W2eff);
        gemm_lds_kernel<2, 64><<<dim3(16, 16, 1), 256, 0, stream>>>(
            t, W2eff, C, nullptr, 2048, D, 0, 0);
        resln_kernel<<<MM, 256, 0, stream>>>(h, C, ln2g + (long)l * D, ln2b + (long)l * D);
    }

    ln_bf16_kernel<<<MM, 256, 0, stream>>>(h, hn, outg, outb);
    cvt_kernel<<<2048, 256, 0, stream>>>(lmW, lmWbf, VV * D / 4);
    // lm_head: 256^2 BK=64 4-phase balanced schedule
    gemm256_kernel<<<dim3(8, 125), 512, 0, stream>>>(hn, lmWbf, (float*)d_out);
}

// Round 8
// 441.872 us; speedup vs baseline: 1.0223x; 1.0021x over previous
//
#include <hip/hip_runtime.h>
#include <math.h>

typedef unsigned short u16;
typedef short s16x8 __attribute__((ext_vector_type(8)));
typedef float f32x4 __attribute__((ext_vector_type(4)));
typedef u16 u16x4 __attribute__((ext_vector_type(4)));
typedef int i32x4 __attribute__((ext_vector_type(4)));

#define D 1024
#define MM 2048   // B*S
#define HH 512
#define VV 32000

static __device__ __forceinline__ u16 f2bf(float f) {
    union { float f; unsigned int i; } c; c.f = f;
    unsigned int x = c.i;
    return (u16)((x + 0x7fffu + ((x >> 16) & 1u)) >> 16);  // RNE
}
static __device__ __forceinline__ float sigm(float x) { return 1.0f / (1.0f + expf(-x)); }

// async global->LDS, 16B per lane, LDS dest = wave-uniform base + lane*16
static __device__ __forceinline__ void load_lds16(const u16* g, u16* l) {
    __builtin_amdgcn_global_load_lds(
        (const __attribute__((address_space(1))) unsigned int*)g,
        (__attribute__((address_space(3))) unsigned int*)l, 16, 0, 0);
}

// ---------------- f32 -> bf16 convert ----------------
__global__ __launch_bounds__(256) void cvt_kernel(const float* __restrict__ in,
                                                  u16* __restrict__ out, const int n4)
{
    for (int i = blockIdx.x * 256 + threadIdx.x; i < n4; i += gridDim.x * 256) {
        f32x4 v = ((const f32x4*)in)[i];
        u16x4 o;
#pragma unroll
        for (int j = 0; j < 4; j++) o[j] = f2bf(v[j]);
        ((u16x4*)out)[i] = o;
    }
}

// ---------------- embed ----------------
__global__ __launch_bounds__(256) void embed_kernel(const int* __restrict__ ids,
    const float* __restrict__ emb, const float* __restrict__ pos, float* __restrict__ h)
{
    const int m = blockIdx.x;
    const int s = m & 1023;
    const long id = ids[m];
    const int d = threadIdx.x * 4;
    f32x4 ev = *(const f32x4*)&emb[id * D + d];
    f32x4 pv = *(const f32x4*)&pos[(long)s * D + d];
    f32x4 o;
#pragma unroll
    for (int i = 0; i < 4; i++) o[i] = ev[i] + pv[i];
    *(f32x4*)&h[(long)m * D + d] = o;
}

// ---------------- layernorm(f32) -> bf16 ----------------
__global__ __launch_bounds__(256) void ln_bf16_kernel(const float* __restrict__ h,
    u16* __restrict__ out, const float* __restrict__ g, const float* __restrict__ b)
{
    const int row = blockIdx.x;
    const int d = threadIdx.x * 4;
    f32x4 x = *(const f32x4*)&h[(long)row * D + d];
    float s = x[0] + x[1] + x[2] + x[3];
    float ss = x[0]*x[0] + x[1]*x[1] + x[2]*x[2] + x[3]*x[3];
#pragma unroll
    for (int off = 32; off; off >>= 1) { s += __shfl_xor(s, off); ss += __shfl_xor(ss, off); }
    __shared__ float red[8];
    const int wid = threadIdx.x >> 6;
    if ((threadIdx.x & 63) == 0) { red[wid] = s; red[4 + wid] = ss; }
    __syncthreads();
    s = red[0] + red[1] + red[2] + red[3];
    ss = red[4] + red[5] + red[6] + red[7];
    const float mu = s * (1.0f / D);
    const float rstd = rsqrtf(ss * (1.0f / D) - mu * mu + 1e-5f);
    f32x4 gv = *(const f32x4*)&g[d];
    f32x4 bv = *(const f32x4*)&b[d];
    u16x4 o;
#pragma unroll
    for (int i = 0; i < 4; i++) o[i] = f2bf((x[i] - mu) * rstd * gv[i] + bv[i]);
    *(u16x4*)&out[(long)row * D + d] = o;
}

// ---------------- h = LN(h + 0.3*C) ----------------
__global__ __launch_bounds__(256) void resln_kernel(float* __restrict__ h,
    const float* __restrict__ c, const float* __restrict__ g, const float* __restrict__ b)
{
    const int row = blockIdx.x;
    const int d = threadIdx.x * 4;
    f32x4 x = *(const f32x4*)&h[(long)row * D + d];
    f32x4 cv = *(const f32x4*)&c[(long)row * D + d];
#pragma unroll
    for (int i = 0; i < 4; i++) x[i] += 0.3f * cv[i];
    float s = x[0] + x[1] + x[2] + x[3];
    float ss = x[0]*x[0] + x[1]*x[1] + x[2]*x[2] + x[3]*x[3];
#pragma unroll
    for (int off = 32; off; off >>= 1) { s += __shfl_xor(s, off); ss += __shfl_xor(ss, off); }
    __shared__ float red[8];
    const int wid = threadIdx.x >> 6;
    if ((threadIdx.x & 63) == 0) { red[wid] = s; red[4 + wid] = ss; }
    __syncthreads();
    s = red[0] + red[1] + red[2] + red[3];
    ss = red[4] + red[5] + red[6] + red[7];
    const float mu = s * (1.0f / D);
    const float rstd = rsqrtf(ss * (1.0f / D) - mu * mu + 1e-5f);
    f32x4 gv = *(const f32x4*)&g[d];
    f32x4 bv = *(const f32x4*)&b[d];
    f32x4 o;
#pragma unroll
    for (int i = 0; i < 4; i++) o[i] = (x[i] - mu) * rstd * gv[i] + bv[i];
    *(f32x4*)&h[(long)row * D + d] = o;
}

// ---------------- exc scales ----------------
__global__ void exc_kernel(const float* __restrict__ pW, const float* __restrict__ pb,
                           float* __restrict__ sc)
{
    if (threadIdx.x == 0 && blockIdx.x == 0) {
        const float NS = 1.0f / (1.0f + expf(-0.70710678118654752f));
        float e[4], sum = 0.0f;
        for (int k = 0; k < 4; k++) {
            float a = pb[k];
            for (int j = 0; j < 4; j++) a += 0.5f * pW[k * 4 + j];
            e[k] = 0.6f * sigm(a) + 0.4f * NS;
            sum += e[k];
        }
        for (int k = 0; k < 4; k++) sc[k] = e[k] / sum;
    }
}

// ---------------- W2eff scale+convert ----------------
__global__ __launch_bounds__(256) void scale_w2_kernel(
    const float* __restrict__ W2l, const float* __restrict__ gatel,
    const float* __restrict__ tors, const float* __restrict__ sc,
    u16* __restrict__ W2eff)
{
    const int n = blockIdx.x >> 1;
    const int half = blockIdx.x & 1;
    const int kh = half * 1024 + threadIdx.x * 4;
    const int k = kh >> 9;
    const int hh = kh & 511;
    const float f = sigm(gatel[k * D + n] + tors[n]) * sc[k];
    f32x4 w = *(const f32x4*)&W2l[((long)k * D + n) * HH + hh];
    u16x4 o;
#pragma unroll
    for (int i = 0; i < 4; i++) o[i] = f2bf(w[i] * f);
    *(u16x4*)&W2eff[(long)n * 2048 + kh] = o;
}

// ---------------- layer GEMM (m97 structure, 128xBN tile) ----------------
template<int EPI, int BN>
__global__ __launch_bounds__(256) void gemm_lds_kernel(
    const u16* __restrict__ A, const u16* __restrict__ W,
    float* __restrict__ Cf, u16* __restrict__ Cb,
    const int K, const long ldc, const long strideWz, const long strideCz)
{
    W += (long)blockIdx.z * strideWz;
    if (EPI == 1) Cb += (long)blockIdx.z * strideCz;
    else          Cf += (long)blockIdx.z * strideCz;

    const int gx = gridDim.x;
    const int nwg = gx * gridDim.y;
    int lin = blockIdx.y * gx + blockIdx.x;
    lin = (lin & 7) * (nwg >> 3) + (lin >> 3);
    const int bm = (lin % gx) * 128;
    const int bn = (lin / gx) * BN;

    __shared__ __align__(16) u16 As[128 * 32];
    __shared__ __align__(16) u16 Bs[BN * 32];

    const int tid = threadIdx.x;
    const int lane = tid & 63;
    const int w = tid >> 6;
    const int wm = (w >> 1) * 64;
    const int wn = (w & 1) * (BN / 2);
    const int lr = lane & 15;
    const int lkb = (lane >> 4) * 16;

    const int srow = lane >> 2;
    const int scol = (lane & 3) * 8;

    constexpr int NA = 8;
    constexpr int NB = BN / 16;
    constexpr int NIT = (NA + NB) / 4;

    f32x4 acc[4][BN / 32];
#pragma unroll
    for (int i = 0; i < 4; i++)
#pragma unroll
        for (int j = 0; j < BN / 32; j++) acc[i][j] = f32x4{0.f, 0.f, 0.f, 0.f};

    for (int k0 = 0; k0 < K; k0 += 32) {
        __syncthreads();
#pragma unroll
        for (int it = 0; it < NIT; ++it) {
            const int c = w + it * 4;
            if (c < NA) {
                load_lds16(&A[(long)(bm + c * 16 + srow) * K + k0 + scol], &As[c * 512]);
            } else {
                const int c2 = c - NA;
                load_lds16(&W[(long)(bn + c2 * 16 + srow) * K + k0 + scol], &Bs[c2 * 512]);
            }
        }
        __syncthreads();
        s16x8 a[4], b[BN / 32];
#pragma unroll
        for (int i = 0; i < 4; i++)
            a[i] = *(const s16x8*)((const char*)As + (wm + i * 16 + lr) * 64 + lkb);
#pragma unroll
        for (int j = 0; j < BN / 32; j++)
            b[j] = *(const s16x8*)((const char*)Bs + (wn + j * 16 + lr) * 64 + lkb);
#pragma unroll
        for (int i = 0; i < 4; i++)
#pragma unroll
            for (int j = 0; j < BN / 32; j++)
                acc[i][j] = __builtin_amdgcn_mfma_f32_16x16x32_bf16(a[i], b[j], acc[i][j], 0, 0, 0);
    }

    const int r0 = (lane >> 4) * 4;
#pragma unroll
    for (int i = 0; i < 4; i++) {
#pragma unroll
        for (int j = 0; j < BN / 32; j++) {
            const int n = bn + wn + j * 16 + lr;
#pragma unroll
            for (int r = 0; r < 4; r++) {
                const int m = bm + wm + i * 16 + r0 + r;
                const float v = acc[i][j][r];
                if (EPI == 0) {
                    Cf[(long)m * ldc + n] = v;
                } else if (EPI == 1) {
                    const float gel = 0.5f * v * (1.0f + erff(v * 0.70710678118654752f));
                    Cb[(long)m * ldc + n] = f2bf(gel);
                } else {
                    Cf[(long)m * ldc + n] += v;
                }
            }
        }
    }
}

// ================= lm_head GEMM: 256x256, BK=64, 2 phases/K-tile, frag prefetch =================
// C[2048,32000] = A[2048,1024] @ W[32000,1024]^T, f32 out. 512 thr = 8 waves (2M x 4N).
// LDS 128KB fragment-linear (zero conflicts). REGISTER DOUBLE-BUFFER: each phase issues
// the 12 ds_reads for the NEXT phase, then runs 32 MFMA on the prefetched frags — the
// compiler's counted lgkmcnt(12) lets LDS delivery overlap the MFMA cluster (the r7
// bottleneck). One barrier/phase; vmcnt(4) per phase (exactly covers the 2 units the
// next phase reads); stage targets proven-dead slots (unit u -> slot u&7).

#define AU16  16384   // u16 per A (or B) double-buffer region = 32KB
#define HALFU 8192    // u16 per 128-row half = 16KB
#define BB0   32768   // u16 offset of B region

__global__ __launch_bounds__(512, 2) void gemm256_kernel(
    const u16* __restrict__ Ag, const u16* __restrict__ Wg, float* __restrict__ C)
{
    __shared__ __align__(16) u16 lds[65536];  // 128KB

    // XCD-chunked bijective swizzle (nwg = 8*125 = 1000, %8 == 0)
    const int nwg = gridDim.x * gridDim.y;
    int lin = blockIdx.y * gridDim.x + blockIdx.x;
    lin = (lin & 7) * (nwg >> 3) + (lin >> 3);
    const int bm = (lin & 7) * 256;
    const int bn = (lin >> 3) * 256;

    const int tid = threadIdx.x;
    const int lane = tid & 63;
    const int w = tid >> 6;     // 0..7
    const int wm = w >> 2;      // 0..1  (M half)
    const int wn = w & 3;       // 0..3  (N quarter)

    // staging: wave w owns fragment-row fr=w of both halves; lane l supplies
    // global element (row = half*128 + w*16 + (l&15), k = kt*64 + kk*32 + (l>>4)*8)
    const u16* aSrc = Ag + (long)(bm + w * 16 + (lane & 15)) * 1024 + ((lane >> 4) * 8);
    const u16* bSrc = Wg + (long)(bn + w * 16 + (lane & 15)) * 1024 + ((lane >> 4) * 8);
    u16* aDst = lds + w * 1024;
    u16* bDst = lds + BB0 + w * 1024;

    auto stageA = [&](int kt, int b, int kk) {
        const long co = (long)kt * 64 + kk * 32;
        load_lds16(aSrc + co,               aDst + b * AU16 + kk * 512);
        load_lds16(aSrc + co + 128 * 1024L, aDst + b * AU16 + HALFU + kk * 512);
    };
    auto stageB = [&](int kt, int b, int kk) {
        const long co = (long)kt * 64 + kk * 32;
        load_lds16(bSrc + co,               bDst + b * AU16 + kk * 512);
        load_lds16(bSrc + co + 128 * 1024L, bDst + b * AU16 + HALFU + kk * 512);
    };

    // fragment-linear reads: chunk base + lane*16B -> conflict-free
    const u16* aRd = lds + wm * HALFU + lane * 8;
    const u16* bRd = lds + BB0 + (wn >> 1) * HALFU + (wn & 1) * 4096 + lane * 8;

    f32x4 acc[8][4];
#pragma unroll
    for (int i = 0; i < 8; ++i)
#pragma unroll
        for (int j = 0; j < 4; ++j) acc[i][j] = f32x4{0.f, 0.f, 0.f, 0.f};

    s16x8 F0[12], F1[12];   // [0..7]=A frags, [8..11]=B frags

    // prologue: units 0..5 = tile0 {Ak0,Bk0,Ak1,Bk1} + tile1 {Ak0,Bk0}
    stageA(0, 0, 0); stageB(0, 0, 0);
    stageA(0, 0, 1); stageB(0, 0, 1);
    stageA(1, 1, 0); stageB(1, 1, 0);
    asm volatile("s_waitcnt vmcnt(4)" ::: "memory");   // units 0..3 (tile0) landed
    __builtin_amdgcn_s_barrier();
    __builtin_amdgcn_sched_barrier(0);

    // read frags for phase 0: tile0 kk0 buf0
#pragma unroll
    for (int i = 0; i < 8; ++i) F0[i] = *(const s16x8*)(aRd + i * 1024);
#pragma unroll
    for (int j = 0; j < 4; ++j) F0[8 + j] = *(const s16x8*)(bRd + j * 1024);

    // phase p: MFMA frags(p) [in fu]; load frags(p+1) [into fl]; stage units {6+2p,7+2p}
    auto phase = [&](int p, s16x8 (&fu)[12], s16x8 (&fl)[12]) {
        const int pr = p + 1;
        const int Tr = (pr >> 1) & 15, kkr = pr & 1, br = Tr & 1;
        const u16* aR = aRd + br * AU16 + kkr * 512;
        const u16* bR = bRd + br * AU16 + kkr * 512;
#pragma unroll
        for (int i = 0; i < 8; ++i) fl[i] = *(const s16x8*)(aR + i * 1024);
#pragma unroll
        for (int j = 0; j < 4; ++j) fl[8 + j] = *(const s16x8*)(bR + j * 1024);
        const int us = 6 + 2 * p;
        const int Ts = (us >> 2) & 15, kks = (us >> 1) & 1, bs = Ts & 1;
        stageA(Ts, bs, kks);
        stageB(Ts, bs, kks);
        __builtin_amdgcn_sched_barrier(0);
        __builtin_amdgcn_s_setprio(1);
#pragma unroll
        for (int j = 0; j < 4; ++j)
#pragma unroll
            for (int i = 0; i < 8; ++i)
                acc[i][j] = __builtin_amdgcn_mfma_f32_16x16x32_bf16(fu[i], fu[8 + j], acc[i][j], 0, 0, 0);
        __builtin_amdgcn_s_setprio(0);
        __builtin_amdgcn_sched_barrier(0);
        asm volatile("s_waitcnt vmcnt(4)" ::: "memory");   // units {2p+2,2p+3} landed
        __builtin_amdgcn_s_barrier();
        __builtin_amdgcn_sched_barrier(0);
    };

    for (int p = 0; p < 32; p += 2) {
        phase(p,     F0, F1);
        phase(p + 1, F1, F0);
    }

    // drain in-flight dummy stages before block retires (LDS dealloc safety)
    asm volatile("s_waitcnt vmcnt(0)" ::: "memory");

    // epilogue: C/D layout col = lane&15, row = (lane>>4)*4 + reg
    const int r0 = (lane >> 4) * 4;
    const int cl = lane & 15;
#pragma unroll
    for (int i = 0; i < 8; ++i)
#pragma unroll
        for (int j = 0; j < 4; ++j) {
            const long m = bm + wm * 128 + i * 16 + r0;
            const int n = bn + wn * 64 + j * 16 + cl;
#pragma unroll
            for (int rr = 0; rr < 4; ++rr)
                C[(m + rr) * (long)VV + n] = acc[i][j][rr];
        }
}

extern "C" void kernel_launch(void* const* d_in, const int* in_sizes, int n_in,
                              void* d_out, int out_size, void* d_ws, size_t ws_size,
                              hipStream_t stream)
{
    (void)in_sizes; (void)n_in; (void)out_size; (void)ws_size;
    const int*   ids   = (const int*)d_in[0];
    const float* emb   = (const float*)d_in[1];
    const float* pos   = (const float*)d_in[2];
    const float* tors  = (const float*)d_in[3];
    const float* ln1g  = (const float*)d_in[4];
    const float* ln1b  = (const float*)d_in[5];
    const float* baseW = (const float*)d_in[6];
    const float* W1    = (const float*)d_in[7];
    const float* W2    = (const float*)d_in[8];
    const float* gate  = (const float*)d_in[9];
    const float* propW = (const float*)d_in[10];
    const float* propb = (const float*)d_in[11];
    const float* ln2g  = (const float*)d_in[12];
    const float* ln2b  = (const float*)d_in[13];
    const float* outg  = (const float*)d_in[14];
    const float* outb  = (const float*)d_in[15];
    const float* lmW   = (const float*)d_in[16];

    char* ws = (char*)d_ws;
    float* h     = (float*)(ws);                    // 0..8 MB
    u16*   hn    = (u16*)  (ws + (8l  << 20));      // 8..12 MB
    u16*   bWbf  = (u16*)  (ws + (12l << 20));      // 12..14 MB
    u16*   W1bf  = (u16*)  (ws + (14l << 20));      // 14..18 MB
    float* C     = (float*)(ws + (18l << 20));      // 18..26 MB
    u16*   t     = (u16*)  (ws + (26l << 20));      // 26..34 MB
    u16*   W2eff = (u16*)  (ws + (34l << 20));      // 34..38 MB
    float* sc    = (float*)(ws + (38l << 20));      // 16 B
    u16*   lmWbf = (u16*)  (ws + (12l << 20));      // overlay: 12..74.5 MB

    embed_kernel<<<MM, 256, 0, stream>>>(ids, emb, pos, h);

    for (int l = 0; l < 2; l++) {
        exc_kernel<<<1, 64, 0, stream>>>(propW + l * 16, propb + l * 4, sc);
        ln_bf16_kernel<<<MM, 256, 0, stream>>>(h, hn, ln1g + (long)l * D, ln1b + (long)l * D);
        cvt_kernel<<<1024, 256, 0, stream>>>(baseW + (long)l * D * D, bWbf, D * D / 4);
        cvt_kernel<<<2048, 256, 0, stream>>>(W1 + (long)l * 4 * HH * D, W1bf, 4 * HH * D / 4);
        gemm_lds_kernel<0, 64><<<dim3(16, 16, 1), 256, 0, stream>>>(
            hn, bWbf, C, nullptr, D, D, 0, 0);
        gemm_lds_kernel<1, 64><<<dim3(16, 8, 4), 256, 0, stream>>>(
            hn, W1bf, nullptr, t, D, 2048, (long)HH * D, 512);
        scale_w2_kernel<<<2048, 256, 0, stream>>>(
            W2 + (long)l * 4 * D * HH, gate + (long)l * 4 * D, tors, sc, W2eff);
        gemm_lds_kernel<2, 64><<<dim3(16, 16, 1), 256, 0, stream>>>(
            t, W2eff, C, nullptr, 2048, D, 0, 0);
        resln_kernel<<<MM, 256, 0, stream>>>(h, C, ln2g + (long)l * D, ln2b + (long)l * D);
    }

    ln_bf16_kernel<<<MM, 256, 0, stream>>>(h, hn, outg, outb);
    cvt_kernel<<<2048, 256, 0, stream>>>(lmW, lmWbf, VV * D / 4);
    // lm_head: 256^2 BK=64, frag-prefetch overlapped schedule
    gemm256_kernel<<<dim3(8, 125), 512, 0, stream>>>(hn, lmWbf, (float*)d_out);
}